// Round 1
// baseline (120.752 us; speedup 1.0000x reference)
//
#include <hip/hip_runtime.h>

#define CH 30
#define CELLS 49
#define ROW 1470           // 49*30 floats per batch row
#define RPB 4              // rows per block, one wave per row
#define NPAIR 735          // ROW/2 float2 pairs
#define ITS 12             // ceil(735/64) pairs per lane, fully hoisted

__device__ __forceinline__ float waveReduce(float v) {
    #pragma unroll
    for (int o = 32; o > 0; o >>= 1) v += __shfl_xor(v, o, 64);
    return v;
}

// One wave per batch row; 4 rows per block. Body is wrapped in a wave-uniform
// `if (r < B)` so every wave reaches the single end-of-kernel barrier used for
// the block-level partial reduction (ws shrinks 4x vs per-wave partials).
__global__ __launch_bounds__(256) void yolo_main(const float* __restrict__ pred,
                                                 const float* __restrict__ targ,
                                                 float* __restrict__ ws, int B,
                                                 int NB) {
    const int w = threadIdx.x >> 6;
    const int lane = threadIdx.x & 63;
    const int r = blockIdx.x * RPB + w;

    __shared__ float4 boxS[RPB][2 * CELLS];  // pred boxes xyxy (broadcast reads)
    __shared__ int clist[RPB][CELLS];
    __shared__ float sred[RPB][3];

    float cls = 0.f, objc = 0.f, coord = 0.f;

    if (r < B) {                             // wave-uniform
        const float* P = pred + (size_t)r * ROW;
        const float* T = targ + (size_t)r * ROW;
        const float2* P2 = (const float2*)P;
        const float2* T2 = (const float2*)T;

        // ---- issue conf load AND all 24 stream loads before any consumption ----
        const int cl = lane < CELLS ? lane : CELLS - 1;
        const float conf = T[cl * CH + 4];

        float2 pv[ITS], tv[ITS];
        #pragma unroll
        for (int it = 0; it < ITS; ++it) {
            const int j = lane + it * 64;
            const int jc = j < NPAIR ? j : NPAIR - 1;   // clamp, gate at consume
            pv[it] = P2[jc];
            tv[it] = T2[jc];
        }

        // ---- obj mask (waits only on the conf load) ----
        const bool isObj = (lane < CELLS) && (conf > 0.f);
        const unsigned long long mask = __ballot(isObj);
        const int nObj = __popcll(mask);
        if (isObj) clist[w][__popcll(mask & ((1ull << lane) - 1ull))] = lane;

        // ---- branch-free consume of the stream ----
        #pragma unroll
        for (int it = 0; it < ITS; ++it) {
            const int j = lane + it * 64;
            const bool valid = j < NPAIR;
            const int cell = (j * 17477) >> 18;          // j/15 for j<=767
            const int ch0 = 2 * (j - cell * 15);         // even channel of the pair
            const float wobj = (float)((mask >> cell) & 1ull);
            const float dx = pv[it].x - tv[it].x;
            const float dy = pv[it].y - tv[it].y;
            // class loss: channels 10..29, obj cells only
            cls += (valid && ch0 >= 10) ? wobj * (dx * dx + dy * dy) : 0.f;
            // noobj conf loss (x0.5 folded): ch4 (.x of pair 4) + ch9 (.y of pair 8)
            const float nn = (ch0 == 4 ? dx * dx : 0.f) + (ch0 == 8 ? dy * dy : 0.f);
            objc += valid ? 0.5f * (1.f - wobj) * nn : 0.f;
        }

        const int nBox = 2 * nObj;

        // ---- masked pred boxes -> xyxy in LDS (global reads are L1-warm) ----
        for (int e = lane; e < nBox; e += 64) {
            const int c = clist[w][e >> 1];
            const float* pb = P + c * CH + (e & 1) * 5;
            const float cx = pb[0], cy = pb[1], bw = pb[2], bh = pb[3];
            boxS[w][e] = make_float4(cx - 0.5f * bw, cy - 0.5f * bh,
                                     cx + 0.5f * bw, cy + 0.5f * bh);
        }

        // ---- per masked target box: max IoU over masked pred boxes; losses ----
        for (int e = lane; e < nBox; e += 64) {
            const int c = clist[w][e >> 1];
            const float* tb = T + c * CH + (e & 1) * 5;
            const float tcx = tb[0], tcy = tb[1], tw = tb[2], th = tb[3];
            const float tx1 = tcx - 0.5f * tw, ty1 = tcy - 0.5f * th;
            const float tx2 = tcx + 0.5f * tw, ty2 = tcy + 0.5f * th;
            const float ta = (tx2 - tx1) * (ty2 - ty1);
            float maxiou = 0.f;
            for (int i = 0; i < nBox; ++i) {
                const float4 pb4 = boxS[w][i];          // wave-uniform addr = broadcast
                const float lx = fmaxf(pb4.x, tx1), ly = fmaxf(pb4.y, ty1);
                const float rx = fminf(pb4.z, tx2), ry = fminf(pb4.w, ty2);
                const float iw = fmaxf(rx - lx, 0.f), ih = fmaxf(ry - ly, 0.f);
                const float inter = iw * ih;
                const float pa = (pb4.z - pb4.x) * (pb4.w - pb4.y);
                const float un = pa + ta - inter;
                const float iou = inter / (un > 0.f ? un : 1.f);
                maxiou = fmaxf(maxiou, iou);
            }
            if (maxiou != 0.f) {                        // cmask
                const float* pb = P + c * CH + (e & 1) * 5;
                const float dcx = pb[0] - tcx, dcy = pb[1] - tcy;
                coord += dcx * dcx + dcy * dcy;
                const float dw = sqrtf(pb[2]) - sqrtf(tw);
                const float dh = sqrtf(pb[3]) - sqrtf(th);
                coord += dw * dw + dh * dh;
                const float dc = pb[4] - tb[4];
                objc += dc * dc;
            }
        }
    }

    // ---- wave reduce, then block reduce (one barrier), one triple per block ----
    cls = waveReduce(cls); objc = waveReduce(objc); coord = waveReduce(coord);
    if (lane == 0) { sred[w][0] = cls; sred[w][1] = objc; sred[w][2] = coord; }
    __syncthreads();
    if (threadIdx.x == 0) {
        float C = 0.f, O = 0.f, X = 0.f;
        #pragma unroll
        for (int k = 0; k < RPB; ++k) { C += sred[k][0]; O += sred[k][1]; X += sred[k][2]; }
        ws[blockIdx.x] = C;
        ws[NB + blockIdx.x] = O;
        ws[2 * NB + blockIdx.x] = X;
    }
}

__global__ __launch_bounds__(1024) void yolo_reduce(const float* __restrict__ ws,
                                                    float* __restrict__ out,
                                                    int NB, float invB) {
    const int tid = threadIdx.x;
    const int w = tid >> 6, lane = tid & 63;
    float c = 0.f, o = 0.f, x = 0.f;
    for (int i = tid; i < NB; i += 1024) {
        c += ws[i];
        o += ws[NB + i];
        x += ws[2 * NB + i];
    }
    c = waveReduce(c); o = waveReduce(o); x = waveReduce(x);
    __shared__ float sred[16][3];
    if (lane == 0) { sred[w][0] = c; sred[w][1] = o; sred[w][2] = x; }
    __syncthreads();
    if (tid == 0) {
        float C = 0.f, O = 0.f, X = 0.f;
        #pragma unroll
        for (int k = 0; k < 16; ++k) { C += sred[k][0]; O += sred[k][1]; X += sred[k][2]; }
        const float bcls = C * invB;
        const float bobj = O * invB;          // noobj*0.5 folded upstream
        const float bcoord = X * 5.0f * invB; // COORD_LAMBDA
        out[0] = bcls + bobj + bcoord;
        out[1] = bcls;
        out[2] = bobj;
        out[3] = bcoord;
    }
}

extern "C" void kernel_launch(void* const* d_in, const int* in_sizes, int n_in,
                              void* d_out, int out_size, void* d_ws, size_t ws_size,
                              hipStream_t stream) {
    const float* pred = (const float*)d_in[0];
    const float* targ = (const float*)d_in[1];
    float* ws = (float*)d_ws;
    float* out = (float*)d_out;
    const int B = in_sizes[0] / ROW;
    const int NB = (B + RPB - 1) / RPB;

    yolo_main<<<NB, 256, 0, stream>>>(pred, targ, ws, B, NB);
    yolo_reduce<<<1, 1024, 0, stream>>>(ws, out, NB, 1.0f / (float)B);
}